// Round 5
// baseline (193.818 us; speedup 1.0000x reference)
//
#include <hip/hip_runtime.h>
#include <hip/hip_bf16.h>

// out[b,o,n] = sum_{k<19,c<64} x[b,c,neigh[n,k]] * W[o,k*64+c] + bias[o]
// B=4, N_VERTS=40962, K_RING=19, C=64.
//
// R13b: R13 with the compile fix (reduce_kernel used HIP float4 with
// __builtin_nontemporal_store; clang requires a real vector type ->
// use floatx4 ext_vector).
// (a) conv is wall-limited at ~5 TB/s gather-request throughput =
//     (~64 outstanding lines/CU) x 64B / ~500cyc avg latency. 26% of
//     gathers miss L2 (5.25MB batch slice > 4MB XCD L2). Fix: split
//     channels in half -> 2.6MB slices, one per XCD (slice = b*2+kc),
//     fully L2-resident -> avg latency ~215cyc -> ~2x ceiling. Cross-kc
//     sum: kc0 writes out(+bias) fp32, kc1 writes bf16 partial to ws,
//     reduce_kernel adds. All output stores non-temporal to not thrash
//     the resident gather set.
// (b) transpose_kernel was the HIDDEN half of dur_us (~75us, just under
//     the top-5 cutoff of 77.7): ~150 instrs/thread, instruction-bound.
//     Vectorized: 4 float4 global loads instead of 16 scalar.

#define NV   40962
#define KR   19
#define CIN  64
#define COUT 64
#define NB   4
#define NTILES 321   // ceil(NV/128)

typedef __bf16 bf16;
typedef __bf16 bf16x8 __attribute__((ext_vector_type(8)));
typedef float  floatx4 __attribute__((ext_vector_type(4)));

#define XT_ELEMS ((size_t)NB * NV * CIN)               // also = NB*COUT*NV
#define WB_OFF   ((XT_ELEMS * 2 + 255) & ~(size_t)255)
#define WF_BYTES ((size_t)COUT * KR * CIN * 2)
#define P1_OFF   ((WB_OFF + WF_BYTES + 255) & ~(size_t)255)
#define WS_SPLIT (P1_OFF + XT_ELEMS * 2)               // ~42.1 MB
#define WS_MID   (WB_OFF + WF_BYTES)                   // ~21.2 MB

// ---------------------------------------------------------------------------
// Kernel 1: x (B,C,N) fp32 -> xt2[b][kc][v][32ch] bf16 (64B line per row).
// Phase1 vectorized: float4 along v (4 loads/thread, was 16 scalar).
// LDS stride 65 keeps both scalar sides ~conflict-free (2-way max).
// ---------------------------------------------------------------------------
__global__ __launch_bounds__(256) void transpose_kernel(
    const float* __restrict__ x, bf16* __restrict__ xt)
{
    __shared__ float tile[64 * 65];
    const int b  = blockIdx.y;
    const int v0 = blockIdx.x * 64;
    const int t  = threadIdx.x;

    if (v0 + 64 <= NV) {
        #pragma unroll
        for (int r = 0; r < 4; ++r) {
            int flat = r * 256 + t;
            int c    = flat >> 4;
            int v4   = (flat & 15) * 4;
            floatx4 val = *(const floatx4*)&x[((size_t)(b * CIN + c)) * NV + v0 + v4];
            tile[(v4 + 0) * 65 + c] = val.x;
            tile[(v4 + 1) * 65 + c] = val.y;
            tile[(v4 + 2) * 65 + c] = val.z;
            tile[(v4 + 3) * 65 + c] = val.w;
        }
    } else {
        // tail tile (1 of 641): scalar clamped path
        const int vl = t & 63;
        const int c0 = t >> 6;
        const int vg = min(v0 + vl, NV - 1);
        #pragma unroll
        for (int p = 0; p < 16; ++p) {
            int c = c0 * 16 + p;
            tile[vl * 65 + c] = x[((size_t)(b * CIN + c)) * NV + vg];
        }
    }
    __syncthreads();

    const int v = t >> 2;
    const int q = t & 3;
    if (v0 + v < NV) {
        #pragma unroll
        for (int p = 0; p < 2; ++p) {
            int chunk = q + p * 4;              // 8 channels
            bf16x8 o;
            #pragma unroll
            for (int j = 0; j < 8; ++j)
                o[j] = (bf16)tile[v * 65 + chunk * 8 + j];
            int kc = chunk >> 2;
            size_t dst = ((size_t)((b * 2 + kc) * NV + v0 + v)) * 32 + (chunk & 3) * 8;
            __builtin_nontemporal_store(o, (bf16x8*)&xt[dst]);
        }
    }
}

// ---------------------------------------------------------------------------
// Kernel 1b: W fp32 (64x1216) -> bf16 MFMA A-fragments, kc-major:
// frag F = (kc*KR + ring)*4 + ot; lane L holds 8 bf16:
//   Wf[(F*64+L)*8 + j] = W[ot*16 + (L&15)][ring*64 + kc*32 + (L>>4)*8 + j]
// ---------------------------------------------------------------------------
__global__ __launch_bounds__(256) void convw_kernel(
    const float* __restrict__ W, bf16* __restrict__ Wf)
{
    const int idx = blockIdx.x * 256 + threadIdx.x;
    if (idx >= 2 * KR * 4 * 64) return;
    const int lane = idx & 63;
    const int ot   = (idx >> 6) & 3;
    const int q    = idx >> 8;                 // kc*KR + ring
    const int kc   = (q >= KR) ? 1 : 0;
    const int ring = q - kc * KR;
    const int row  = ot * 16 + (lane & 15);
    const int col0 = ring * 64 + kc * 32 + (lane >> 4) * 8;
    const float* src = W + (size_t)row * (KR * CIN) + col0;
    floatx4 a = *(const floatx4*)(src);
    floatx4 c = *(const floatx4*)(src + 4);
    bf16x8 o;
    o[0] = (bf16)a.x; o[1] = (bf16)a.y; o[2] = (bf16)a.z; o[3] = (bf16)a.w;
    o[4] = (bf16)c.x; o[5] = (bf16)c.y; o[6] = (bf16)c.z; o[7] = (bf16)c.w;
    *(bf16x8*)(Wf + (size_t)idx * 8) = o;
}

// ---------------------------------------------------------------------------
// Kernel 2: kc-split gather-GEMM. Block (b,kc,tile); slice = b*2+kc = XCD.
// Per wave: 32 verts x 64 outs, K=608 (its kc half). Per ring: 2 gathers
// (64B L2-resident rows) + 4 W frags + 8 MFMA. Issue order per iter:
// idx(r+3), W(r+1), x(r+2) -> consume of W(r) is vmcnt(10), x stays in
// flight (never drains). kc0: out = acc + bias (fp32, nt). kc1: P1 = acc
// (bf16, nt).
// ---------------------------------------------------------------------------
__global__ __launch_bounds__(256, 3) void conv_split_kernel(
    const int*   __restrict__ neigh,
    const bf16*  __restrict__ xt,     // [b][kc][v][32] bf16
    const bf16*  __restrict__ Wf,     // kc-major fragments
    const float* __restrict__ bias,
    float*       __restrict__ out,    // (B, 64, NV) fp32
    bf16*        __restrict__ P1)     // (B, 64, NV) bf16 partial (kc=1)
{
    const int i     = blockIdx.x;
    const int slice = i & 7;                   // -> XCD
    const int b     = slice >> 1;
    const int kc    = slice & 1;
    const int tile  = i >> 3;                  // 0..320

    const int t    = threadIdx.x;
    const int wv   = t >> 6;
    const int lane = t & 63;
    const int l15  = lane & 15;
    const int g    = lane >> 4;

    const int n0 = tile * 128 + wv * 32;
    int nn[2], ib[2];
    #pragma unroll
    for (int s = 0; s < 2; ++s) {
        nn[s] = n0 + s * 16 + l15;
        ib[s] = min(nn[s], NV - 1) * KR;
    }

    const bf16* xb = xt + ((size_t)slice * NV) * 32 + g * 8;      // + v*32
    const bf16* wb = Wf + (size_t)kc * (KR * 2048) + lane * 8;    // + r*2048 + ot*512

    floatx4 acc[2][4];
    #pragma unroll
    for (int s = 0; s < 2; ++s)
        #pragma unroll
        for (int o = 0; o < 4; ++o)
            acc[s][o] = (floatx4){0.f, 0.f, 0.f, 0.f};

    // ---- prologue: idx rings 1,2; gathers 0,1; W ring 0
    int inxt[2], i3rd[2];
    bf16x8 xf[2], xg[2], wf[4];
    #pragma unroll
    for (int s = 0; s < 2; ++s) {
        int v0i = neigh[ib[s] + 0];
        inxt[s] = neigh[ib[s] + 1];
        i3rd[s] = neigh[ib[s] + 2];
        int v = ((unsigned)v0i < (unsigned)NV) ? v0i : 0;
        xf[s] = *(const bf16x8*)(xb + (size_t)v * 32);
    }
    #pragma unroll
    for (int f = 0; f < 4; ++f)
        wf[f] = *(const bf16x8*)(wb + f * 512);
    #pragma unroll
    for (int s = 0; s < 2; ++s) {
        int v = ((unsigned)inxt[s] < (unsigned)NV) ? inxt[s] : 0;
        xg[s] = *(const bf16x8*)(xb + (size_t)v * 32);
    }

    #pragma unroll
    for (int r = 0; r < KR; ++r) {
        int inew[2];
        bf16x8 wg[4], xh[2];

        if (r + 3 < KR) {
            #pragma unroll
            for (int s = 0; s < 2; ++s)
                inew[s] = neigh[ib[s] + r + 3];
        }
        if (r + 1 < KR) {                       // W first (vmcnt ordering)
            const bf16* wr = wb + (size_t)(r + 1) * 2048;
            #pragma unroll
            for (int f = 0; f < 4; ++f)
                wg[f] = *(const bf16x8*)(wr + f * 512);
        }
        if (r + 2 < KR) {                       // x after W: stays in flight
            #pragma unroll
            for (int s = 0; s < 2; ++s) {
                int v = ((unsigned)i3rd[s] < (unsigned)NV) ? i3rd[s] : 0;
                xh[s] = *(const bf16x8*)(xb + (size_t)v * 32);
            }
        }

        __builtin_amdgcn_s_setprio(1);
        #pragma unroll
        for (int ot = 0; ot < 4; ++ot)
            #pragma unroll
            for (int s = 0; s < 2; ++s)
                acc[s][ot] = __builtin_amdgcn_mfma_f32_16x16x32_bf16(
                    wf[ot], xf[s], acc[s][ot], 0, 0, 0);
        __builtin_amdgcn_s_setprio(0);

        // rotate (SSA-renamed under full unroll)
        if (r + 1 < KR) {
            #pragma unroll
            for (int s = 0; s < 2; ++s) xf[s] = xg[s];
            #pragma unroll
            for (int f = 0; f < 4; ++f) wf[f] = wg[f];
        }
        if (r + 2 < KR) {
            #pragma unroll
            for (int s = 0; s < 2; ++s) { xg[s] = xh[s]; inxt[s] = i3rd[s]; i3rd[s] = (r + 3 < KR) ? inew[s] : 0; }
        }
    }

    // ---- epilogue: C/D col=l15 (vertex), row=g*4+ii (output)
    if (kc == 0) {
        #pragma unroll
        for (int ot = 0; ot < 4; ++ot) {
            #pragma unroll
            for (int ii = 0; ii < 4; ++ii) {
                const int o = ot * 16 + g * 4 + ii;
                const float bv = bias[o];
                #pragma unroll
                for (int s = 0; s < 2; ++s) {
                    if (nn[s] < NV)
                        __builtin_nontemporal_store(acc[s][ot][ii] + bv,
                            &out[((size_t)(b * COUT + o)) * NV + nn[s]]);
                }
            }
        }
    } else {
        #pragma unroll
        for (int ot = 0; ot < 4; ++ot) {
            #pragma unroll
            for (int ii = 0; ii < 4; ++ii) {
                const int o = ot * 16 + g * 4 + ii;
                #pragma unroll
                for (int s = 0; s < 2; ++s) {
                    if (nn[s] < NV)
                        __builtin_nontemporal_store((bf16)acc[s][ot][ii],
                            &P1[((size_t)(b * COUT + o)) * NV + nn[s]]);
                }
            }
        }
    }
}

// ---------------------------------------------------------------------------
// Kernel 3: out += P1 (bf16). Pure streaming, nt. (floatx4 ext_vector:
// __builtin_nontemporal_* requires clang vector types, not HIP float4.)
// ---------------------------------------------------------------------------
__global__ __launch_bounds__(256) void reduce_kernel(
    float* __restrict__ out, const bf16* __restrict__ P1)
{
    const size_t total8 = XT_ELEMS / 8;
    for (size_t j = (size_t)blockIdx.x * 256 + threadIdx.x; j < total8;
         j += (size_t)gridDim.x * 256) {
        bf16x8 p = __builtin_nontemporal_load((const bf16x8*)P1 + j);
        floatx4* op = (floatx4*)out + j * 2;
        floatx4 a = __builtin_nontemporal_load(op);
        floatx4 c = __builtin_nontemporal_load(op + 1);
        a.x += (float)p[0]; a.y += (float)p[1]; a.z += (float)p[2]; a.w += (float)p[3];
        c.x += (float)p[4]; c.y += (float)p[5]; c.z += (float)p[6]; c.w += (float)p[7];
        __builtin_nontemporal_store(a, op);
        __builtin_nontemporal_store(c, op + 1);
    }
}

// ---------------------------------------------------------------------------
// Mid fallback (ws fits old budget only): both kc in-block, direct out.
// Same xt2/Wf buffers; R12-style structure.
// ---------------------------------------------------------------------------
__global__ __launch_bounds__(256, 3) void conv_nosplit_kernel(
    const int*   __restrict__ neigh,
    const bf16*  __restrict__ xt,
    const bf16*  __restrict__ Wf,
    const float* __restrict__ bias,
    float*       __restrict__ out)
{
    const int i    = blockIdx.x;
    const int b    = (i & 7) >> 1;
    const int tile = (i >> 3) * 2 + (i & 1);
    if (tile >= NTILES) return;

    const int t    = threadIdx.x;
    const int wv   = t >> 6;
    const int lane = t & 63;
    const int l15  = lane & 15;
    const int g    = lane >> 4;

    const int n0 = tile * 128 + wv * 32;
    int nn[2], ib[2];
    #pragma unroll
    for (int s = 0; s < 2; ++s) {
        nn[s] = n0 + s * 16 + l15;
        ib[s] = min(nn[s], NV - 1) * KR;
    }

    const bf16* xb0 = xt + ((size_t)(b * 2 + 0) * NV) * 32 + g * 8;
    const bf16* xb1 = xt + ((size_t)(b * 2 + 1) * NV) * 32 + g * 8;
    const bf16* wb  = Wf + lane * 8;

    floatx4 acc[2][4];
    #pragma unroll
    for (int s = 0; s < 2; ++s)
        #pragma unroll
        for (int o = 0; o < 4; ++o)
            acc[s][o] = (floatx4){0.f, 0.f, 0.f, 0.f};

    int inxt[2];
    bf16x8 xf[2][2], wf[2][4];
    #pragma unroll
    for (int s = 0; s < 2; ++s) {
        int v0i = neigh[ib[s] + 0];
        inxt[s] = neigh[ib[s] + 1];
        int v = ((unsigned)v0i < (unsigned)NV) ? v0i : 0;
        xf[s][0] = *(const bf16x8*)(xb0 + (size_t)v * 32);
        xf[s][1] = *(const bf16x8*)(xb1 + (size_t)v * 32);
    }
    #pragma unroll
    for (int kc = 0; kc < 2; ++kc)
        #pragma unroll
        for (int f = 0; f < 4; ++f)
            wf[kc][f] = *(const bf16x8*)(wb + (size_t)kc * (KR * 2048) + f * 512);

    #pragma unroll
    for (int r = 0; r < KR; ++r) {
        int inew[2];
        bf16x8 wg[2][4], xg[2][2];
        if (r + 2 < KR) {
            #pragma unroll
            for (int s = 0; s < 2; ++s) inew[s] = neigh[ib[s] + r + 2];
        }
        if (r + 1 < KR) {
            #pragma unroll
            for (int kc = 0; kc < 2; ++kc)
                #pragma unroll
                for (int f = 0; f < 4; ++f)
                    wg[kc][f] = *(const bf16x8*)(wb + (size_t)kc * (KR * 2048)
                                                 + (size_t)(r + 1) * 2048 + f * 512);
            #pragma unroll
            for (int s = 0; s < 2; ++s) {
                int v = ((unsigned)inxt[s] < (unsigned)NV) ? inxt[s] : 0;
                xg[s][0] = *(const bf16x8*)(xb0 + (size_t)v * 32);
                xg[s][1] = *(const bf16x8*)(xb1 + (size_t)v * 32);
            }
        }

        __builtin_amdgcn_s_setprio(1);
        #pragma unroll
        for (int kc = 0; kc < 2; ++kc)
            #pragma unroll
            for (int ot = 0; ot < 4; ++ot)
                #pragma unroll
                for (int s = 0; s < 2; ++s)
                    acc[s][ot] = __builtin_amdgcn_mfma_f32_16x16x32_bf16(
                        wf[kc][ot], xf[s][kc], acc[s][ot], 0, 0, 0);
        __builtin_amdgcn_s_setprio(0);

        if (r + 1 < KR) {
            #pragma unroll
            for (int s = 0; s < 2; ++s) {
                xf[s][0] = xg[s][0];
                xf[s][1] = xg[s][1];
                inxt[s]  = (r + 2 < KR) ? inew[s] : 0;
            }
            #pragma unroll
            for (int kc = 0; kc < 2; ++kc)
                #pragma unroll
                for (int f = 0; f < 4; ++f)
                    wf[kc][f] = wg[kc][f];
        }
    }

    #pragma unroll
    for (int ot = 0; ot < 4; ++ot) {
        #pragma unroll
        for (int ii = 0; ii < 4; ++ii) {
            const int o = ot * 16 + g * 4 + ii;
            const float bv = bias[o];
            #pragma unroll
            for (int s = 0; s < 2; ++s) {
                if (nn[s] < NV)
                    out[((size_t)(b * COUT + o)) * NV + nn[s]] = acc[s][ot][ii] + bv;
            }
        }
    }
}

// ---------------------------------------------------------------------------
// Last-resort fallback (no workspace).
// ---------------------------------------------------------------------------
__global__ __launch_bounds__(64) void fallback_kernel(
    const int*   __restrict__ neigh,
    const float* __restrict__ x,
    const float* __restrict__ W,
    const float* __restrict__ bias,
    float*       __restrict__ out)
{
    __shared__ float xg[KR * CIN];
    const int bn = blockIdx.x;
    const int b  = bn / NV;
    const int n  = bn % NV;
    const int t  = threadIdx.x;

    for (int k = t; k < KR * CIN; k += 64) {
        int r = k / CIN, c = k - r * CIN;
        int v = neigh[n * KR + r];
        v = ((unsigned)v < (unsigned)NV) ? v : 0;
        xg[k] = x[((size_t)(b * CIN + c)) * NV + v];
    }
    __syncthreads();

    float s = bias[t];
    const float* wrow = W + (size_t)t * (KR * CIN);
    for (int k = 0; k < KR * CIN; ++k) s += xg[k] * wrow[k];
    out[((size_t)(b * COUT + t)) * NV + n] = s;
}

// ---------------------------------------------------------------------------
extern "C" void kernel_launch(void* const* d_in, const int* in_sizes, int n_in,
                              void* d_out, int out_size, void* d_ws, size_t ws_size,
                              hipStream_t stream)
{
    const float* x     = (const float*)d_in[0];
    const int*   neigh = (const int*)d_in[1];
    const float* W     = (const float*)d_in[2];
    const float* bias  = (const float*)d_in[3];
    float* out = (float*)d_out;

    if (d_ws != nullptr && ws_size >= WS_MID) {
        bf16* xt = (bf16*)d_ws;
        bf16* Wf = (bf16*)((char*)d_ws + WB_OFF);

        dim3 tgrid((NV + 63) / 64, NB);
        transpose_kernel<<<tgrid, 256, 0, stream>>>(x, xt);
        convw_kernel<<<(2 * KR * 4 * 64 + 255) / 256, 256, 0, stream>>>(W, Wf);

        if (ws_size >= WS_SPLIT) {
            bf16* P1 = (bf16*)((char*)d_ws + P1_OFF);
            conv_split_kernel<<<8 * NTILES, 256, 0, stream>>>(
                neigh, xt, Wf, bias, out, P1);
            reduce_kernel<<<2048, 256, 0, stream>>>(out, P1);
        } else {
            int nblk = 8 * ((NTILES + 1) / 2);   // 1288
            conv_nosplit_kernel<<<nblk, 256, 0, stream>>>(neigh, xt, Wf, bias, out);
        }
    } else {
        fallback_kernel<<<NB * NV, 64, 0, stream>>>(neigh, x, W, bias, out);
    }
}